// Round 12
// baseline (422.004 us; speedup 1.0000x reference)
//
#include <hip/hip_runtime.h>

#define NU     50000
#define NEN    100000
#define NEDGE  2000000
#define NINTER 1000000
#define CH     64
#define NRELM1 9
#define CAPE   64     // padded CSR bucket capacity per entity (Poisson(20): P(deg>=65)~3e-15/bin)
#define CAPU   64     // padded bucket capacity per user

// ---- two-pass CSR build, no fabric atomics / no agent-scope stores ----
#define BINSH   8                                 // 256 nodes per bin
#define NBINE   ((NEN + 255) >> BINSH)            // 391
#define NBINU   ((NU  + 255) >> BINSH)            // 196
#define CHUNKE  2048                              // entity edges per k_bin block (8/thread regs)
#define CHUNKU  1024                              // user edges per k_bin block (4/thread regs)
#define NBE_BLK ((NEDGE  + CHUNKE - 1) / CHUNKE)  // 977
#define NBU_BLK ((NINTER + CHUNKU - 1) / CHUNKU)  // 977
#define DSTRE   416                               // dir row stride (u32): >=NBINE, 128B multiple
#define DSTRU   224                               // >=NBINU, 128B multiple
#define NSTR_E  ((NEN * CH) / 2048)               // 3125 streaming blocks (8 elem/thread)
#define NSTR_U  ((NU * CH + 2047) / 2048)         // 1563
#define NPLACE  (NBINE + NBINU)                   // 587
#define NGEMM0  ((NEN + 127) / 128)               // 782 (512-thread k_pg gemm part)
#define NGEMM   ((NEN + 63) / 64)                 // 1563 (256-thread gemm1 in k_gu)

typedef _Float16 hv2 __attribute__((ext_vector_type(2)));
typedef _Float16 h8  __attribute__((ext_vector_type(8)));
typedef float    f32x4 __attribute__((ext_vector_type(4)));
union P4 { float4 f; hv2 h[4]; };   // 16B = 8 halves

// cvt_pkrtz returns __fp16x2; bit-cast to our hv2 (identical layout)
static __device__ __forceinline__ hv2 pkrtz(float a, float b) {
    return __builtin_bit_cast(hv2, __builtin_amdgcn_cvt_pkrtz(a, b));
}

// QE layout: per node 128 halves = [E(64) | Q(64)], 256B row.

// ---- pass 1: SINGLE-PASS per-chunk bin-sort (edges held in registers; LDS
//      10.1KB -> 8 blocks/CU). Streaming embedding init rides along. ----
__global__ __launch_bounds__(256) void k_bin(
    const float* __restrict__ ue, const float* __restrict__ ee,
    const float* __restrict__ re, const float* __restrict__ wq,
    const float* __restrict__ iw, const int* __restrict__ eidx,
    const int* __restrict__ etype, const int* __restrict__ ii,
    _Float16* __restrict__ QE, float* __restrict__ Eres, float* __restrict__ Ures,
    _Float16* __restrict__ Relh, _Float16* __restrict__ Wt,
    unsigned* __restrict__ dirE, unsigned* __restrict__ dirU,
    int* __restrict__ blkBufE, unsigned long long* __restrict__ blkBufU)
{
    __shared__ long long srt64[CHUNKU];   // 8 KB; entity path uses it as int[CHUNKE]
    __shared__ int hist[512];             // histogram, then running cursors
    __shared__ int segtot[8];
    int* srt = (int*)srt64;
    int b = blockIdx.x, tid = threadIdx.x;
    int lane63 = tid & 63, wv = tid >> 6;

    if (b < NBE_BLK) {                                   // ---- entity edges ----
        int base = b * CHUNKE;
        int n = NEDGE - base; if (n > CHUNKE) n = CHUNKE;
        bool full = (n == CHUNKE);
        int rec[8], bn[8];
#pragma unroll
        for (int k = 0; k < 8; ++k) {                    // single read of all edges
            int i = tid + (k << 8);
            bool a = full || (i < n);
            int h  = a ? eidx[base + i] : 0;
            int t  = a ? eidx[NEDGE + base + i] : 0;
            int rt = a ? etype[base + i] - 1 : 0;
            bn[k]  = a ? (h >> BINSH) : -1;
            rec[k] = (h & 255) | ((t | (rt << 17)) << 8);
        }
        hist[tid] = 0; hist[tid + 256] = 0;
        __syncthreads();
#pragma unroll
        for (int k = 0; k < 8; ++k)
            if (bn[k] >= 0) atomicAdd(&hist[bn[k]], 1);  // LDS atomic
        __syncthreads();
        int v0 = hist[tid], v1 = hist[tid + 256];        // wave-shuffle scan
        int s0 = v0, s1 = v1;
#pragma unroll
        for (int off = 1; off < 64; off <<= 1) {
            int u0 = __shfl_up(s0, off);
            int u1 = __shfl_up(s1, off);
            if (lane63 >= off) { s0 += u0; s1 += u1; }
        }
        if (lane63 == 63) { segtot[wv] = s0; segtot[4 + wv] = s1; }
        __syncthreads();
        int base0 = 0, base1 = 0;
#pragma unroll
        for (int k = 0; k < 8; ++k) {
            int t = segtot[k];
            if (k < wv)     base0 += t;
            if (k < 4 + wv) base1 += t;
        }
        int off0 = base0 + s0 - v0, off1 = base1 + s1 - v1;   // exclusive prefixes
        hist[tid] = off0; hist[tid + 256] = off1;             // become cursors
        __syncthreads();
#pragma unroll
        for (int k = 0; k < 8; ++k)                      // scatter from registers
            if (bn[k] >= 0) { int pos = atomicAdd(&hist[bn[k]], 1); srt[pos] = rec[k]; }
        __syncthreads();
        int4* dst = (int4*)(blkBufE + b * CHUNKE);       // block-private, coalesced
        const int4* s4 = (const int4*)srt;
        for (int j = tid; j < ((n + 3) >> 2); j += 256) dst[j] = s4[j];
        if (tid < NBINE)
            dirE[b * DSTRE + tid]       = ((unsigned)off0 << 16) | (unsigned)v0;
        if (tid + 256 < NBINE)
            dirE[b * DSTRE + tid + 256] = ((unsigned)off1 << 16) | (unsigned)v1;
    } else if (b < NBE_BLK + NBU_BLK) {                  // ---- user-item edges ----
        int ub = b - NBE_BLK;
        int base = ub * CHUNKU;
        int n = NINTER - base; if (n > CHUNKU) n = CHUNKU;
        bool full = (n == CHUNKU);
        unsigned long long rec64[4]; int bn[4];
#pragma unroll
        for (int k = 0; k < 4; ++k) {
            int i = tid + (k << 8);
            bool a = full || (i < n);
            int u = a ? ii[base + i] : 0;
            int e = a ? ii[NINTER + base + i] : 0;
            unsigned w = a ? __float_as_uint(iw[base + i]) : 0u;
            bn[k] = a ? (u >> BINSH) : -1;
            rec64[k] = (unsigned long long)((u & 255) | (e << 8))
                     | ((unsigned long long)w << 32);
        }
        hist[tid] = 0; hist[tid + 256] = 0;
        __syncthreads();
#pragma unroll
        for (int k = 0; k < 4; ++k)
            if (bn[k] >= 0) atomicAdd(&hist[bn[k]], 1);
        __syncthreads();
        int v0 = hist[tid], v1 = hist[tid + 256];
        int s0 = v0, s1 = v1;
#pragma unroll
        for (int off = 1; off < 64; off <<= 1) {
            int u0 = __shfl_up(s0, off);
            int u1 = __shfl_up(s1, off);
            if (lane63 >= off) { s0 += u0; s1 += u1; }
        }
        if (lane63 == 63) { segtot[wv] = s0; segtot[4 + wv] = s1; }
        __syncthreads();
        int base0 = 0, base1 = 0;
#pragma unroll
        for (int k = 0; k < 8; ++k) {
            int t = segtot[k];
            if (k < wv)     base0 += t;
            if (k < 4 + wv) base1 += t;
        }
        int off0 = base0 + s0 - v0, off1 = base1 + s1 - v1;
        hist[tid] = off0; hist[tid + 256] = off1;
        __syncthreads();
#pragma unroll
        for (int k = 0; k < 4; ++k)
            if (bn[k] >= 0) { int pos = atomicAdd(&hist[bn[k]], 1); srt64[pos] = rec64[k]; }
        __syncthreads();
        int4* dst = (int4*)(blkBufU + (size_t)ub * CHUNKU);
        const int4* s4 = (const int4*)srt64;
        for (int j = tid; j < ((n + 1) >> 1); j += 256) dst[j] = s4[j];
        if (tid < NBINU)
            dirU[ub * DSTRU + tid]       = ((unsigned)off0 << 16) | (unsigned)v0;
        if (tid + 256 < NBINU)
            dirU[ub * DSTRU + tid + 256] = ((unsigned)off1 << 16) | (unsigned)v1;
    } else {                                             // ---- streaming init ----
        int sb = b - (NBE_BLK + NBU_BLK);
        if (sb < NSTR_E) {
            int i0 = sb * 2048 + tid * 8;
            float4 a = *(const float4*)(ee + i0);
            float4 c = *(const float4*)(ee + i0 + 4);
            *(float4*)(Eres + i0)     = a;
            *(float4*)(Eres + i0 + 4) = c;
            P4 o;
            o.h[0] = pkrtz(a.x, a.y);
            o.h[1] = pkrtz(a.z, a.w);
            o.h[2] = pkrtz(c.x, c.y);
            o.h[3] = pkrtz(c.z, c.w);
            int node = i0 >> 6, c0 = i0 & 63;            // interleaved E-part
            *(float4*)(QE + (size_t)node * 128 + c0) = o.f;
        } else if (sb < NSTR_E + NSTR_U) {
            int i0 = (sb - NSTR_E) * 2048 + tid * 8;
            if (i0 < NU * CH) {
                *(float4*)(Ures + i0)     = *(const float4*)(ue + i0);
                *(float4*)(Ures + i0 + 4) = *(const float4*)(ue + i0 + 4);
            }
        } else {
            for (int i = tid; i < NRELM1 * CH; i += 256)
                Relh[i] = (_Float16)re[i];
            for (int i = tid; i < CH * CH; i += 256)
                Wt[(i & 63) * 64 + (i >> 6)] = (_Float16)wq[i];   // Wt[c][k] = W[k][c]
        }
    }
}

// ---- merged pass (512 threads): per-bin placement (two interleaved chunk
//      chains per thread: latency overlap) || hop-0 MFMA gemm. ----
__global__ __launch_bounds__(512) void k_pg(
    const unsigned* __restrict__ dirE, const int* __restrict__ blkBufE,
    const unsigned* __restrict__ dirU, const unsigned long long* __restrict__ blkBufU,
    int* __restrict__ cntE, int* __restrict__ csrE,
    int* __restrict__ cntU, unsigned long long* __restrict__ csrU2,
    _Float16* __restrict__ QE, const _Float16* __restrict__ Wt)
{
    __shared__ int cnt[256];
    int b = blockIdx.x, tid = threadIdx.x;
    if (b >= NPLACE) {                          // ---- gemm part ----
        int gb = b - NPLACE;
        int w = tid >> 6, lane = tid & 63;
        int r0 = gb * 128 + w * 16;
        if (r0 >= NEN) return;                  // no barriers below: safe divergence
        int lr = lane & 15, lg = lane >> 4;
        const _Float16* arow = QE + (size_t)(r0 + lr) * 128 + lg * 8;   // E-part
        h8 a0 = *(const h8*)(arow);
        h8 a1 = *(const h8*)(arow + 32);
#pragma unroll
        for (int ct = 0; ct < 4; ++ct) {
            const _Float16* brow = Wt + (ct * 16 + lr) * 64 + lg * 8;
            h8 b0 = *(const h8*)(brow);
            h8 b1 = *(const h8*)(brow + 32);
            f32x4 c = {0.f, 0.f, 0.f, 0.f};
            c = __builtin_amdgcn_mfma_f32_16x16x32_f16(a0, b0, c, 0, 0, 0);
            c = __builtin_amdgcn_mfma_f32_16x16x32_f16(a1, b1, c, 0, 0, 0);
            // C/D: col = lane&15, row = (lane>>4)*4 + r
#pragma unroll
            for (int r = 0; r < 4; ++r)
                QE[(size_t)(r0 + lg * 4 + r) * 128 + 64 + ct * 16 + lr] = (_Float16)c[r];
        }
        return;
    }
    // ---- placement part ----
    if (tid < 256) cnt[tid] = 0;
    __syncthreads();
    if (b < NBINE) {
        unsigned d1 = (tid < NBE_BLK)       ? dirE[tid * DSTRE + b]         : 0;
        unsigned d2 = (tid + 512 < NBE_BLK) ? dirE[(tid + 512) * DSTRE + b] : 0;
        int c1 = d1 & 0xFFFF, c2 = d2 & 0xFFFF;
        const int* s1 = blkBufE + tid * CHUNKE + (d1 >> 16);
        const int* s2 = blkBufE + (tid + 512) * CHUNKE + (d2 >> 16);
        int m = c1 > c2 ? c1 : c2;
        for (int i = 0; i < m; ++i) {                    // two independent chains
            int r1 = (i < c1) ? s1[i] : -1;              // entity rec always >= 0
            int r2 = (i < c2) ? s2[i] : -1;
            if (r1 >= 0) { int nl = r1 & 255; int pos = atomicAdd(&cnt[nl], 1);
                           if (pos < CAPE) csrE[((b << BINSH) + nl) * CAPE + pos] = r1 >> 8; }
            if (r2 >= 0) { int nl = r2 & 255; int pos = atomicAdd(&cnt[nl], 1);
                           if (pos < CAPE) csrE[((b << BINSH) + nl) * CAPE + pos] = r2 >> 8; }
        }
        __syncthreads();
        if (tid < 256) {
            int node = (b << BINSH) + tid;
            if (node < NEN) { int c = cnt[tid]; cntE[node] = c > CAPE ? CAPE : c; }
        }
    } else {
        int ub = b - NBINE;
        unsigned d1 = (tid < NBU_BLK)       ? dirU[tid * DSTRU + ub]         : 0;
        unsigned d2 = (tid + 512 < NBU_BLK) ? dirU[(tid + 512) * DSTRU + ub] : 0;
        int c1 = d1 & 0xFFFF, c2 = d2 & 0xFFFF;
        const unsigned long long* s1 = blkBufU + (size_t)tid * CHUNKU + (d1 >> 16);
        const unsigned long long* s2 = blkBufU + (size_t)(tid + 512) * CHUNKU + (d2 >> 16);
        int m = c1 > c2 ? c1 : c2;
        for (int i = 0; i < m; ++i) {
            if (i < c1) {
                unsigned long long rec = s1[i];
                int nl = (int)rec & 255; int pos = atomicAdd(&cnt[nl], 1);
                if (pos < CAPU)
                    csrU2[((ub << BINSH) + nl) * CAPU + pos] =
                        ((rec & 0xFFFFFFFFull) >> 8) | (rec & 0xFFFFFFFF00000000ull);
            }
            if (i < c2) {
                unsigned long long rec = s2[i];
                int nl = (int)rec & 255; int pos = atomicAdd(&cnt[nl], 1);
                if (pos < CAPU)
                    csrU2[((ub << BINSH) + nl) * CAPU + pos] =
                        ((rec & 0xFFFFFFFFull) >> 8) | (rec & 0xFFFFFFFF00000000ull);
            }
        }
        __syncthreads();
        if (tid < 256) {
            int node = (ub << BINSH) + tid;
            if (node < NU) { int c = cnt[tid]; cntU[node] = c > CAPU ? CAPU : c; }
        }
    }
}

// ---- hop-0 fused (r8 form — verified 100us, DO NOT restructure) ----
__global__ __launch_bounds__(256) void k_fused0(
    const int* __restrict__ cntE, const int* __restrict__ csrE,
    const _Float16* __restrict__ QE, const _Float16* __restrict__ Relh,
    _Float16* __restrict__ QEn, float* __restrict__ Eres,
    const int* __restrict__ cntU, const unsigned long long* __restrict__ csrU2,
    float* __restrict__ Ures)
{
    __shared__ __attribute__((aligned(16))) _Float16 RelL[NRELM1 * 72];
    int tid = threadIdx.x;
    if (tid < 72) *(float4*)(RelL + (tid >> 3) * 72 + (tid & 7) * 8)
                      = *(const float4*)(Relh + tid * 8);
    __syncthreads();

    int pair = blockIdx.x * 4 + (tid >> 6);
    int lane = tid & 63;
    int wid  = pair * 2 + (lane >> 5);
    int s = (lane >> 3) & 3, l = lane & 7;
    int c8 = l * 8;

    if (wid < NEN) {
        int row = wid;
        int cnt = cntE[row];
        int beg = row * CAPE, end = beg + cnt;
        P4 q; q.f = *(const float4*)(QE + (size_t)row * 128 + 64 + c8);
        float acc[8] = {0.f,0.f,0.f,0.f,0.f,0.f,0.f,0.f};
        float den = 0.f;

        int a0 = beg + s;
        int iA = (a0 < end) ? csrE[a0] : 0;
        int iB = (a0 + 4 < end) ? csrE[a0 + 4] : 0;
        P4 teA, ktA, rlA;
        {
            const _Float16* bA = QE + (size_t)(iA & 0x1FFFF) * 128 + c8;
            teA.f = *(const float4*)bA;
            ktA.f = *(const float4*)(bA + 64);
            rlA.f = *(const float4*)(RelL + (iA >> 17) * 72 + c8);
        }
        int nit = (cnt + 3) >> 2;
        for (int it = 0; it < nit; ++it) {
            P4 teB, ktB, rlB;
            {
                const _Float16* bB = QE + (size_t)(iB & 0x1FFFF) * 128 + c8;
                teB.f = *(const float4*)bB;
                ktB.f = *(const float4*)(bB + 64);
                rlB.f = *(const float4*)(RelL + (iB >> 17) * 72 + c8);
            }
            int a2 = a0 + (it + 2) * 4;
            int iN = (a2 < end) ? csrE[a2] : 0;
            bool act = (a0 + it * 4) < end;
            float sc = 0.f;
#pragma unroll
            for (int i = 0; i < 4; ++i) {
                hv2 km = ktA.h[i] * rlA.h[i];
                sc = __builtin_amdgcn_fdot2(q.h[i], km, sc, false);
            }
            sc += __shfl_xor(sc, 1);
            sc += __shfl_xor(sc, 2);
            float ex = exp2f(sc * 0.25503489f);          // 1/sqrt(32)*log2(e)
            if (!act) ex = 0.f;
            den += ex;
#pragma unroll
            for (int i = 0; i < 4; ++i) {
                hv2 vm = teA.h[i] * rlA.h[i];
                acc[2*i]   += ex * (float)vm.x;
                acc[2*i+1] += ex * (float)vm.y;
            }
            teA = teB; ktA = ktB; rlA = rlB; iB = iN;
        }
        hv2 pk[4];
#pragma unroll
        for (int i = 0; i < 4; ++i)
            pk[i] = pkrtz(acc[2*i], acc[2*i+1]);
#pragma unroll
        for (int m = 8; m <= 16; m <<= 1) {
#pragma unroll
            for (int i = 0; i < 4; ++i) {
                int v = __shfl_xor(__builtin_bit_cast(int, pk[i]), m);
                pk[i] += __builtin_bit_cast(hv2, v);
            }
            den += __shfl_xor(den, m);
        }
        float af[8];
#pragma unroll
        for (int i = 0; i < 4; ++i) { af[2*i] = (float)pk[i].x; af[2*i+1] = (float)pk[i].y; }
        float invd = (den > 0.f) ? 1.f / den : 0.f;
        float ss = 0.f;
#pragma unroll
        for (int k = 0; k < 8; ++k) { af[k] *= invd; ss += af[k] * af[k]; }
        ss += __shfl_xor(ss, 1); ss += __shfl_xor(ss, 2); ss += __shfl_xor(ss, 4);
        float inv = 1.f / fmaxf(sqrtf(ss), 1e-12f);
#pragma unroll
        for (int k = 0; k < 8; ++k) af[k] *= inv;
        if (s == 0) {
            P4 o;
#pragma unroll
            for (int i = 0; i < 4; ++i)
                o.h[i] = pkrtz(af[2*i], af[2*i+1]);
            *(float4*)(QEn + (size_t)row * 128 + c8) = o.f;     // E-part of next hop
            float4 r0 = *(const float4*)(Eres + (size_t)row * 64 + c8);
            float4 r1 = *(const float4*)(Eres + (size_t)row * 64 + c8 + 4);
            r0.x += af[0]; r0.y += af[1]; r0.z += af[2]; r0.w += af[3];
            r1.x += af[4]; r1.y += af[5]; r1.z += af[6]; r1.w += af[7];
            *(float4*)(Eres + (size_t)row * 64 + c8)     = r0;
            *(float4*)(Eres + (size_t)row * 64 + c8 + 4) = r1;
        }
    } else {
        int row = wid - NEN;
        int cnt = cntU[row];
        int beg = row * CAPU, end = beg + cnt;
        float acc[8] = {0.f,0.f,0.f,0.f,0.f,0.f,0.f,0.f};
        int a0 = beg + s;
        unsigned long long recA = (a0 < end) ? csrU2[a0] : 0ull;
        unsigned long long recB = (a0 + 4 < end) ? csrU2[a0 + 4] : 0ull;
        P4 teA; teA.f = *(const float4*)(QE + (size_t)(unsigned)recA * 128 + c8);
        int nit = (cnt + 3) >> 2;
        for (int it = 0; it < nit; ++it) {
            P4 teB; teB.f = *(const float4*)(QE + (size_t)(unsigned)recB * 128 + c8);
            int a2 = a0 + (it + 2) * 4;
            unsigned long long recN = (a2 < end) ? csrU2[a2] : 0ull;
            float wA = __uint_as_float((unsigned)(recA >> 32));
#pragma unroll
            for (int i = 0; i < 4; ++i) {
                acc[2*i]   += wA * (float)teA.h[i].x;
                acc[2*i+1] += wA * (float)teA.h[i].y;
            }
            teA = teB; recA = recB; recB = recN;
        }
        hv2 pk[4];
#pragma unroll
        for (int i = 0; i < 4; ++i)
            pk[i] = pkrtz(acc[2*i], acc[2*i+1]);
#pragma unroll
        for (int m = 8; m <= 16; m <<= 1) {
#pragma unroll
            for (int i = 0; i < 4; ++i) {
                int v = __shfl_xor(__builtin_bit_cast(int, pk[i]), m);
                pk[i] += __builtin_bit_cast(hv2, v);
            }
        }
        float af[8];
#pragma unroll
        for (int i = 0; i < 4; ++i) { af[2*i] = (float)pk[i].x; af[2*i+1] = (float)pk[i].y; }
        float ss = 0.f;
#pragma unroll
        for (int k = 0; k < 8; ++k) ss += af[k] * af[k];
        ss += __shfl_xor(ss, 1); ss += __shfl_xor(ss, 2); ss += __shfl_xor(ss, 4);
        float inv = 1.f / fmaxf(sqrtf(ss), 1e-12f);
        if (s == 0) {
            float4 r0 = *(const float4*)(Ures + (size_t)row * 64 + c8);
            float4 r1 = *(const float4*)(Ures + (size_t)row * 64 + c8 + 4);
            r0.x += af[0] * inv; r0.y += af[1] * inv; r0.z += af[2] * inv; r0.w += af[3] * inv;
            r1.x += af[4] * inv; r1.y += af[5] * inv; r1.z += af[6] * inv; r1.w += af[7] * inv;
            *(float4*)(Ures + (size_t)row * 64 + c8)     = r0;
            *(float4*)(Ures + (size_t)row * 64 + c8 + 4) = r1;
        }
    }
}

// ---- hop-1: gemm1 || users. Users read only E-halves; gemm writes only
//      Q-halves — disjoint 128B lines, safe to co-schedule. ----
__global__ __launch_bounds__(256) void k_gu(
    _Float16* __restrict__ QE, const _Float16* __restrict__ Wt,
    const int* __restrict__ cntU, const unsigned long long* __restrict__ csrU2,
    float* __restrict__ Ures)
{
    int tid = threadIdx.x;
    if (blockIdx.x < NGEMM) {                   // ---- gemm1 ----
        int w = tid >> 6, lane = tid & 63;
        int r0 = blockIdx.x * 64 + w * 16;
        if (r0 >= NEN) return;
        int lr = lane & 15, lg = lane >> 4;
        const _Float16* arow = QE + (size_t)(r0 + lr) * 128 + lg * 8;
        h8 a0 = *(const h8*)(arow);
        h8 a1 = *(const h8*)(arow + 32);
#pragma unroll
        for (int ct = 0; ct < 4; ++ct) {
            const _Float16* brow = Wt + (ct * 16 + lr) * 64 + lg * 8;
            h8 b0 = *(const h8*)(brow);
            h8 b1 = *(const h8*)(brow + 32);
            f32x4 c = {0.f, 0.f, 0.f, 0.f};
            c = __builtin_amdgcn_mfma_f32_16x16x32_f16(a0, b0, c, 0, 0, 0);
            c = __builtin_amdgcn_mfma_f32_16x16x32_f16(a1, b1, c, 0, 0, 0);
#pragma unroll
            for (int r = 0; r < 4; ++r)
                QE[(size_t)(r0 + lg * 4 + r) * 128 + 64 + ct * 16 + lr] = (_Float16)c[r];
        }
        return;
    }
    // ---- users hop-1 ----
    int pair = (blockIdx.x - NGEMM) * 4 + (tid >> 6);
    int lane = tid & 63;
    int row = pair * 2 + (lane >> 5);           // exact: 6250*8 = 50000
    int s = (lane >> 3) & 3, l = lane & 7;
    int c8 = l * 8;
    int cnt = cntU[row];
    int beg = row * CAPU, end = beg + cnt;
    float acc[8] = {0.f,0.f,0.f,0.f,0.f,0.f,0.f,0.f};
    int a0 = beg + s;
    unsigned long long recA = (a0 < end) ? csrU2[a0] : 0ull;
    unsigned long long recB = (a0 + 4 < end) ? csrU2[a0 + 4] : 0ull;
    P4 teA; teA.f = *(const float4*)(QE + (size_t)(unsigned)recA * 128 + c8);
    int nit = (cnt + 3) >> 2;
    for (int it = 0; it < nit; ++it) {
        P4 teB; teB.f = *(const float4*)(QE + (size_t)(unsigned)recB * 128 + c8);
        int a2 = a0 + (it + 2) * 4;
        unsigned long long recN = (a2 < end) ? csrU2[a2] : 0ull;
        float wA = __uint_as_float((unsigned)(recA >> 32));
#pragma unroll
        for (int i = 0; i < 4; ++i) {
            acc[2*i]   += wA * (float)teA.h[i].x;
            acc[2*i+1] += wA * (float)teA.h[i].y;
        }
        teA = teB; recA = recB; recB = recN;
    }
    hv2 pk[4];
#pragma unroll
    for (int i = 0; i < 4; ++i)
        pk[i] = pkrtz(acc[2*i], acc[2*i+1]);
#pragma unroll
    for (int m = 8; m <= 16; m <<= 1) {
#pragma unroll
        for (int i = 0; i < 4; ++i) {
            int v = __shfl_xor(__builtin_bit_cast(int, pk[i]), m);
            pk[i] += __builtin_bit_cast(hv2, v);
        }
    }
    float af[8];
#pragma unroll
    for (int i = 0; i < 4; ++i) { af[2*i] = (float)pk[i].x; af[2*i+1] = (float)pk[i].y; }
    float ss = 0.f;
#pragma unroll
    for (int k = 0; k < 8; ++k) ss += af[k] * af[k];
    ss += __shfl_xor(ss, 1); ss += __shfl_xor(ss, 2); ss += __shfl_xor(ss, 4);
    float inv = 1.f / fmaxf(sqrtf(ss), 1e-12f);
    if (s == 0) {
        float4 r0 = *(const float4*)(Ures + (size_t)row * 64 + c8);
        float4 r1 = *(const float4*)(Ures + (size_t)row * 64 + c8 + 4);
        r0.x += af[0] * inv; r0.y += af[1] * inv; r0.z += af[2] * inv; r0.w += af[3] * inv;
        r1.x += af[4] * inv; r1.y += af[5] * inv; r1.z += af[6] * inv; r1.w += af[7] * inv;
        *(float4*)(Ures + (size_t)row * 64 + c8)     = r0;
        *(float4*)(Ures + (size_t)row * 64 + c8 + 4) = r1;
    }
}

// ---- hop-1 entities only (no QEn store) ----
__global__ __launch_bounds__(256) void k_fusedE(
    const int* __restrict__ cntE, const int* __restrict__ csrE,
    const _Float16* __restrict__ QE, const _Float16* __restrict__ Relh,
    float* __restrict__ Eres)
{
    __shared__ __attribute__((aligned(16))) _Float16 RelL[NRELM1 * 72];
    int tid = threadIdx.x;
    if (tid < 72) *(float4*)(RelL + (tid >> 3) * 72 + (tid & 7) * 8)
                      = *(const float4*)(Relh + tid * 8);
    __syncthreads();

    int pair = blockIdx.x * 4 + (tid >> 6);
    int lane = tid & 63;
    int row  = pair * 2 + (lane >> 5);          // exact: 12500*8 = 100000
    int s = (lane >> 3) & 3, l = lane & 7;
    int c8 = l * 8;

    int cnt = cntE[row];
    int beg = row * CAPE, end = beg + cnt;
    P4 q; q.f = *(const float4*)(QE + (size_t)row * 128 + 64 + c8);
    float acc[8] = {0.f,0.f,0.f,0.f,0.f,0.f,0.f,0.f};
    float den = 0.f;

    int a0 = beg + s;
    int iA = (a0 < end) ? csrE[a0] : 0;
    int iB = (a0 + 4 < end) ? csrE[a0 + 4] : 0;
    P4 teA, ktA, rlA;
    {
        const _Float16* bA = QE + (size_t)(iA & 0x1FFFF) * 128 + c8;
        teA.f = *(const float4*)bA;
        ktA.f = *(const float4*)(bA + 64);
        rlA.f = *(const float4*)(RelL + (iA >> 17) * 72 + c8);
    }
    int nit = (cnt + 3) >> 2;
    for (int it = 0; it < nit; ++it) {
        P4 teB, ktB, rlB;
        {
            const _Float16* bB = QE + (size_t)(iB & 0x1FFFF) * 128 + c8;
            teB.f = *(const float4*)bB;
            ktB.f = *(const float4*)(bB + 64);
            rlB.f = *(const float4*)(RelL + (iB >> 17) * 72 + c8);
        }
        int a2 = a0 + (it + 2) * 4;
        int iN = (a2 < end) ? csrE[a2] : 0;
        bool act = (a0 + it * 4) < end;
        float sc = 0.f;
#pragma unroll
        for (int i = 0; i < 4; ++i) {
            hv2 km = ktA.h[i] * rlA.h[i];
            sc = __builtin_amdgcn_fdot2(q.h[i], km, sc, false);
        }
        sc += __shfl_xor(sc, 1);
        sc += __shfl_xor(sc, 2);
        float ex = exp2f(sc * 0.25503489f);
        if (!act) ex = 0.f;
        den += ex;
#pragma unroll
        for (int i = 0; i < 4; ++i) {
            hv2 vm = teA.h[i] * rlA.h[i];
            acc[2*i]   += ex * (float)vm.x;
            acc[2*i+1] += ex * (float)vm.y;
        }
        teA = teB; ktA = ktB; rlA = rlB; iB = iN;
    }
    hv2 pk[4];
#pragma unroll
    for (int i = 0; i < 4; ++i)
        pk[i] = pkrtz(acc[2*i], acc[2*i+1]);
#pragma unroll
    for (int m = 8; m <= 16; m <<= 1) {
#pragma unroll
        for (int i = 0; i < 4; ++i) {
            int v = __shfl_xor(__builtin_bit_cast(int, pk[i]), m);
            pk[i] += __builtin_bit_cast(hv2, v);
        }
        den += __shfl_xor(den, m);
    }
    float af[8];
#pragma unroll
    for (int i = 0; i < 4; ++i) { af[2*i] = (float)pk[i].x; af[2*i+1] = (float)pk[i].y; }
    float invd = (den > 0.f) ? 1.f / den : 0.f;
    float ss = 0.f;
#pragma unroll
    for (int k = 0; k < 8; ++k) { af[k] *= invd; ss += af[k] * af[k]; }
    ss += __shfl_xor(ss, 1); ss += __shfl_xor(ss, 2); ss += __shfl_xor(ss, 4);
    float inv = 1.f / fmaxf(sqrtf(ss), 1e-12f);
    if (s == 0) {
        float4 r0 = *(const float4*)(Eres + (size_t)row * 64 + c8);
        float4 r1 = *(const float4*)(Eres + (size_t)row * 64 + c8 + 4);
        r0.x += af[0] * inv; r0.y += af[1] * inv; r0.z += af[2] * inv; r0.w += af[3] * inv;
        r1.x += af[4] * inv; r1.y += af[5] * inv; r1.z += af[6] * inv; r1.w += af[7] * inv;
        *(float4*)(Eres + (size_t)row * 64 + c8)     = r0;
        *(float4*)(Eres + (size_t)row * 64 + c8 + 4) = r1;
    }
}

extern "C" void kernel_launch(void* const* d_in, const int* in_sizes, int n_in,
                              void* d_out, int out_size, void* d_ws, size_t ws_size,
                              hipStream_t stream)
{
    const float* ue = (const float*)d_in[0];
    const float* ee = (const float*)d_in[1];
    const float* re = (const float*)d_in[2];
    const float* wq = (const float*)d_in[3];
    const float* iw = (const float*)d_in[4];
    const int* eidx  = (const int*)d_in[5];
    const int* etype = (const int*)d_in[6];
    const int* ii    = (const int*)d_in[7];

    float* Eres = (float*)d_out;                 // residuals live in d_out directly
    float* Ures = Eres + (size_t)NEN * CH;

    // ws carve (~107 MB):
    // [Relh 2KB][Wt 8KB][QEA 25.6M][QEB 25.6M][cntE][cntU][csrE 25.6M][csrU2 25.6M][dirE][dirU]
    _Float16* Relh = (_Float16*)d_ws;                     // 576 used, 1024 reserved
    _Float16* Wt   = Relh + 1024;                         // 4096 halves (f16 W^T)
    _Float16* QEA  = Wt + 4096;                           // NEN*128 halves
    _Float16* QEB  = QEA + (size_t)NEN * 128;
    int* cntE      = (int*)(QEB + (size_t)NEN * 128);
    int* cntU      = cntE + NEN;
    int* csrE      = cntU + NU;                           // NEN*CAPE ints
    unsigned long long* csrU2 = (unsigned long long*)(csrE + (size_t)NEN * CAPE);
    unsigned* dirE = (unsigned*)(csrU2 + (size_t)NU * CAPU);   // 977*416 u32
    unsigned* dirU = dirE + NBE_BLK * DSTRE;                   // 977*224 u32
    // chunk buffers alias QEB (first written by hop-0 k_fused0, strictly after
    // k_pg placement reads complete). 16.0 MB < 25.6 MB.
    int* blkBufE   = (int*)QEB;                                    // 8.0 MB
    unsigned long long* blkBufU =
        (unsigned long long*)((char*)QEB + (size_t)NBE_BLK * CHUNKE * 4);  // 8.0 MB

    k_bin<<<NBE_BLK + NBU_BLK + NSTR_E + NSTR_U + 1, 256, 0, stream>>>(
        ue, ee, re, wq, iw, eidx, etype, ii,
        QEA, Eres, Ures, Relh, Wt, dirE, dirU, blkBufE, blkBufU);
    k_pg<<<NPLACE + NGEMM0, 512, 0, stream>>>(dirE, blkBufE, dirU, blkBufU,
                                              cntE, csrE, cntU, csrU2, QEA, Wt);
    k_fused0<<<(NEN + NU) / 8, 256, 0, stream>>>(cntE, csrE, QEA, Relh,
                                                 QEB, Eres, cntU, csrU2, Ures);
    k_gu<<<NGEMM + NU / 8, 256, 0, stream>>>(QEB, Wt, cntU, csrU2, Ures);
    k_fusedE<<<NEN / 8, 256, 0, stream>>>(cntE, csrE, QEB, Relh, Eres);
}

// Round 13
// 406.684 us; speedup vs baseline: 1.0377x; 1.0377x over previous
//
#include <hip/hip_runtime.h>

#define NU     50000
#define NEN    100000
#define NEDGE  2000000
#define NINTER 1000000
#define CH     64
#define NRELM1 9
#define CAPE   64     // padded CSR bucket capacity per entity (Poisson(20): P(deg>=65)~3e-15/bin)
#define CAPU   64     // padded bucket capacity per user

// ---- two-pass CSR build, no fabric atomics / no agent-scope stores ----
#define BINSH   8                                 // 256 nodes per bin
#define NBINE   ((NEN + 255) >> BINSH)            // 391
#define NBINU   ((NU  + 255) >> BINSH)            // 196
#define CHUNKE  4096                              // entity edges per k_bin block
#define CHUNKU  2048                              // user edges per k_bin block (8B recs, 16KB LDS)
#define NBE_BLK ((NEDGE  + CHUNKE - 1) / CHUNKE)  // 489
#define NBU_BLK ((NINTER + CHUNKU - 1) / CHUNKU)  // 489
#define DSTRE   416                               // dir row stride (u32): >=NBINE, 128B multiple
#define DSTRU   224                               // >=NBINU, 128B multiple
#define NSTR_E  ((NEN * CH) / 2048)               // 3125 streaming blocks (8 elem/thread)
#define NSTR_U  ((NU * CH + 2047) / 2048)         // 1563
#define NPLACE  (NBINE + NBINU)                   // 587
#define NGEMM0  ((NEN + 127) / 128)               // 782 (512-thread k_pg gemm part)
#define NGEMM   ((NEN + 63) / 64)                 // 1563 (256-thread hop-1 gemm)

typedef _Float16 hv2 __attribute__((ext_vector_type(2)));
typedef _Float16 h8  __attribute__((ext_vector_type(8)));
typedef float    f32x4 __attribute__((ext_vector_type(4)));
union P4 { float4 f; hv2 h[4]; };   // 16B = 8 halves

// cvt_pkrtz returns __fp16x2; bit-cast to our hv2 (identical layout)
static __device__ __forceinline__ hv2 pkrtz(float a, float b) {
    return __builtin_bit_cast(hv2, __builtin_amdgcn_cvt_pkrtz(a, b));
}

// QE layout: per node 128 halves = [E(64) | Q(64)], 256B row.

// ---- pass 1: per-chunk bin-sort in LDS (wave-shuffle scan, 2 barriers),
//      write sorted chunk to block-private region + per-(chunk,bin) directory.
//      Streaming embedding init rides along as trailing blocks. ----
__global__ __launch_bounds__(256) void k_bin(
    const float* __restrict__ ue, const float* __restrict__ ee,
    const float* __restrict__ re, const float* __restrict__ wq,
    const float* __restrict__ iw, const int* __restrict__ eidx,
    const int* __restrict__ etype, const int* __restrict__ ii,
    _Float16* __restrict__ QE, float* __restrict__ Eres, float* __restrict__ Ures,
    _Float16* __restrict__ Relh, _Float16* __restrict__ Wt,
    unsigned* __restrict__ dirE, unsigned* __restrict__ dirU,
    int* __restrict__ blkBufE, unsigned long long* __restrict__ blkBufU)
{
    __shared__ long long srt64[CHUNKU];   // 16 KB; entity path uses it as int[CHUNKE]
    __shared__ int hist[512];
    __shared__ int sc[512];
    __shared__ int segtot[8];
    int* srt = (int*)srt64;
    int b = blockIdx.x, tid = threadIdx.x;
    int lane63 = tid & 63, wv = tid >> 6;

    if (b < NBE_BLK) {                                   // ---- entity edges ----
        hist[tid] = 0; hist[tid + 256] = 0;
        __syncthreads();
        int base = b * CHUNKE;
        int n = NEDGE - base; if (n > CHUNKE) n = CHUNKE;
        for (int i = tid; i < n; i += 256)
            atomicAdd(&hist[eidx[base + i] >> BINSH], 1);        // LDS atomic
        __syncthreads();
        // wave-shuffle exclusive scan over 512 entries (2 barriers)
        {
            int v0 = hist[tid], v1 = hist[tid + 256];
            int s0 = v0, s1 = v1;
#pragma unroll
            for (int off = 1; off < 64; off <<= 1) {
                int u0 = __shfl_up(s0, off);
                int u1 = __shfl_up(s1, off);
                if (lane63 >= off) { s0 += u0; s1 += u1; }
            }
            if (lane63 == 63) { segtot[wv] = s0; segtot[4 + wv] = s1; }
            __syncthreads();
            int base0 = 0, base1 = 0;
#pragma unroll
            for (int k = 0; k < 8; ++k) {
                int t = segtot[k];
                if (k < wv)     base0 += t;
                if (k < 4 + wv) base1 += t;
            }
            sc[tid]       = base0 + s0 - v0;     // exclusive prefix
            sc[tid + 256] = base1 + s1 - v1;
            __syncthreads();
        }
        for (int i = tid; i < n; i += 256) {                     // re-read (L2-hot), LDS scatter
            int h  = eidx[base + i];
            int t  = eidx[NEDGE + base + i];
            int rt = etype[base + i] - 1;
            int pos = atomicAdd(&sc[h >> BINSH], 1);
            srt[pos] = (h & 255) | ((t | (rt << 17)) << 8);
        }
        __syncthreads();
        int4* dst = (int4*)(blkBufE + b * CHUNKE);               // block-private, coalesced
        const int4* s4 = (const int4*)srt;
        for (int j = tid; j < ((n + 3) >> 2); j += 256) dst[j] = s4[j];
        for (int bin = tid; bin < NBINE; bin += 256)             // dir: (off<<16)|cnt
            dirE[b * DSTRE + bin] =
                ((unsigned)(sc[bin] - hist[bin]) << 16) | (unsigned)hist[bin];
    } else if (b < NBE_BLK + NBU_BLK) {                  // ---- user-item edges ----
        hist[tid] = 0; hist[tid + 256] = 0;
        __syncthreads();
        int ub = b - NBE_BLK;
        int base = ub * CHUNKU;
        int n = NINTER - base; if (n > CHUNKU) n = CHUNKU;
        for (int i = tid; i < n; i += 256)
            atomicAdd(&hist[ii[base + i] >> BINSH], 1);
        __syncthreads();
        {
            int v0 = hist[tid], v1 = hist[tid + 256];
            int s0 = v0, s1 = v1;
#pragma unroll
            for (int off = 1; off < 64; off <<= 1) {
                int u0 = __shfl_up(s0, off);
                int u1 = __shfl_up(s1, off);
                if (lane63 >= off) { s0 += u0; s1 += u1; }
            }
            if (lane63 == 63) { segtot[wv] = s0; segtot[4 + wv] = s1; }
            __syncthreads();
            int base0 = 0, base1 = 0;
#pragma unroll
            for (int k = 0; k < 8; ++k) {
                int t = segtot[k];
                if (k < wv)     base0 += t;
                if (k < 4 + wv) base1 += t;
            }
            sc[tid]       = base0 + s0 - v0;
            sc[tid + 256] = base1 + s1 - v1;
            __syncthreads();
        }
        for (int i = tid; i < n; i += 256) {
            int u = ii[base + i];
            int e = ii[NINTER + base + i];
            unsigned w = __float_as_uint(iw[base + i]);
            int pos = atomicAdd(&sc[u >> BINSH], 1);
            srt64[pos] = (unsigned long long)((u & 255) | (e << 8))
                       | ((unsigned long long)w << 32);
        }
        __syncthreads();
        int4* dst = (int4*)(blkBufU + (size_t)ub * CHUNKU);
        const int4* s4 = (const int4*)srt64;
        for (int j = tid; j < ((n + 1) >> 1); j += 256) dst[j] = s4[j];
        for (int bin = tid; bin < NBINU; bin += 256)
            dirU[ub * DSTRU + bin] =
                ((unsigned)(sc[bin] - hist[bin]) << 16) | (unsigned)hist[bin];
    } else {                                             // ---- streaming init ----
        int sb = b - (NBE_BLK + NBU_BLK);
        if (sb < NSTR_E) {
            int i0 = sb * 2048 + tid * 8;
            float4 a = *(const float4*)(ee + i0);
            float4 c = *(const float4*)(ee + i0 + 4);
            *(float4*)(Eres + i0)     = a;
            *(float4*)(Eres + i0 + 4) = c;
            P4 o;
            o.h[0] = pkrtz(a.x, a.y);
            o.h[1] = pkrtz(a.z, a.w);
            o.h[2] = pkrtz(c.x, c.y);
            o.h[3] = pkrtz(c.z, c.w);
            int node = i0 >> 6, c0 = i0 & 63;            // interleaved E-part
            *(float4*)(QE + (size_t)node * 128 + c0) = o.f;
        } else if (sb < NSTR_E + NSTR_U) {
            int i0 = (sb - NSTR_E) * 2048 + tid * 8;
            if (i0 < NU * CH) {
                *(float4*)(Ures + i0)     = *(const float4*)(ue + i0);
                *(float4*)(Ures + i0 + 4) = *(const float4*)(ue + i0 + 4);
            }
        } else {
            for (int i = tid; i < NRELM1 * CH; i += 256)
                Relh[i] = (_Float16)re[i];
            for (int i = tid; i < CH * CH; i += 256)
                Wt[(i & 63) * 64 + (i >> 6)] = (_Float16)wq[i];   // Wt[c][k] = W[k][c]
        }
    }
}

// ---- merged pass (512 threads): per-bin placement (blocks 0..NPLACE, 489
//      parallel chunk-walkers with ~10-record chains) || hop-0 MFMA gemm
//      (128 rows/block, 8 waves). Independent work, co-scheduled. ----
__global__ __launch_bounds__(512) void k_pg(
    const unsigned* __restrict__ dirE, const int* __restrict__ blkBufE,
    const unsigned* __restrict__ dirU, const unsigned long long* __restrict__ blkBufU,
    int* __restrict__ cntE, int* __restrict__ csrE,
    int* __restrict__ cntU, unsigned long long* __restrict__ csrU2,
    _Float16* __restrict__ QE, const _Float16* __restrict__ Wt)
{
    __shared__ int cnt[256];
    int b = blockIdx.x, tid = threadIdx.x;
    if (b >= NPLACE) {                          // ---- gemm part ----
        int gb = b - NPLACE;
        int w = tid >> 6, lane = tid & 63;
        int r0 = gb * 128 + w * 16;
        if (r0 >= NEN) return;                  // no barriers below: safe divergence
        int lr = lane & 15, lg = lane >> 4;
        const _Float16* arow = QE + (size_t)(r0 + lr) * 128 + lg * 8;   // E-part
        h8 a0 = *(const h8*)(arow);
        h8 a1 = *(const h8*)(arow + 32);
#pragma unroll
        for (int ct = 0; ct < 4; ++ct) {
            const _Float16* brow = Wt + (ct * 16 + lr) * 64 + lg * 8;
            h8 b0 = *(const h8*)(brow);
            h8 b1 = *(const h8*)(brow + 32);
            f32x4 c = {0.f, 0.f, 0.f, 0.f};
            c = __builtin_amdgcn_mfma_f32_16x16x32_f16(a0, b0, c, 0, 0, 0);
            c = __builtin_amdgcn_mfma_f32_16x16x32_f16(a1, b1, c, 0, 0, 0);
            // C/D: col = lane&15, row = (lane>>4)*4 + r
#pragma unroll
            for (int r = 0; r < 4; ++r)
                QE[(size_t)(r0 + lg * 4 + r) * 128 + 64 + ct * 16 + lr] = (_Float16)c[r];
        }
        return;
    }
    // ---- placement part ----
    if (tid < 256) cnt[tid] = 0;
    __syncthreads();
    if (b < NBINE) {
        if (tid < NBE_BLK) {
            unsigned d = dirE[tid * DSTRE + b];
            int off = d >> 16, c = d & 0xFFFF;
            const int* src = blkBufE + tid * CHUNKE + off;
            for (int i = 0; i < c; ++i) {
                int rec = src[i];
                int nl = rec & 255;
                int pos = atomicAdd(&cnt[nl], 1);
                if (pos < CAPE) csrE[((b << BINSH) + nl) * CAPE + pos] = rec >> 8;
            }
        }
        __syncthreads();
        if (tid < 256) {
            int node = (b << BINSH) + tid;
            if (node < NEN) { int c = cnt[tid]; cntE[node] = c > CAPE ? CAPE : c; }
        }
    } else {
        int ub = b - NBINE;
        if (tid < NBU_BLK) {
            unsigned d = dirU[tid * DSTRU + ub];
            int off = d >> 16, c = d & 0xFFFF;
            const unsigned long long* src = blkBufU + (size_t)tid * CHUNKU + off;
            for (int i = 0; i < c; ++i) {
                unsigned long long rec = src[i];
                int nl = (int)rec & 255;
                int pos = atomicAdd(&cnt[nl], 1);
                if (pos < CAPU)
                    csrU2[((ub << BINSH) + nl) * CAPU + pos] =
                        ((rec & 0xFFFFFFFFull) >> 8) | (rec & 0xFFFFFFFF00000000ull);
            }
        }
        __syncthreads();
        if (tid < 256) {
            int node = (ub << BINSH) + tid;
            if (node < NU) { int c = cnt[tid]; cntU[node] = c > CAPU ? CAPU : c; }
        }
    }
}

// ---- hop-1 gemm (standalone) ----
__global__ __launch_bounds__(256) void k_gemm(
    _Float16* __restrict__ QE, const _Float16* __restrict__ Wt)
{
    int w = threadIdx.x >> 6, lane = threadIdx.x & 63;
    int r0 = blockIdx.x * 64 + w * 16;
    if (r0 >= NEN) return;
    int lr = lane & 15, lg = lane >> 4;
    const _Float16* arow = QE + (size_t)(r0 + lr) * 128 + lg * 8;   // E-part
    h8 a0 = *(const h8*)(arow);
    h8 a1 = *(const h8*)(arow + 32);
#pragma unroll
    for (int ct = 0; ct < 4; ++ct) {
        const _Float16* brow = Wt + (ct * 16 + lr) * 64 + lg * 8;
        h8 b0 = *(const h8*)(brow);
        h8 b1 = *(const h8*)(brow + 32);
        f32x4 c = {0.f, 0.f, 0.f, 0.f};
        c = __builtin_amdgcn_mfma_f32_16x16x32_f16(a0, b0, c, 0, 0, 0);
        c = __builtin_amdgcn_mfma_f32_16x16x32_f16(a1, b1, c, 0, 0, 0);
#pragma unroll
        for (int r = 0; r < 4; ++r)
            QE[(size_t)(r0 + lg * 4 + r) * 128 + 64 + ct * 16 + lr] = (_Float16)c[r];
    }
}

// ---- fused per-node pass (r8 form — verified 100us, DO NOT restructure):
// Two nodes per wave (half-wave = 32 lanes = 4 slots x 8 lanes). r5-style
// rotation pipeline (r7 manual unroll: -12%; r9 shfl-indices: -30%).
// LAST=true skips the QEn store (hop 1 output feeds nothing).
template<bool LAST>
__global__ __launch_bounds__(256) void k_fused(
    const int* __restrict__ cntE, const int* __restrict__ csrE,
    const _Float16* __restrict__ QE, const _Float16* __restrict__ Relh,
    _Float16* __restrict__ QEn, float* __restrict__ Eres,
    const int* __restrict__ cntU, const unsigned long long* __restrict__ csrU2,
    float* __restrict__ Ures)
{
    __shared__ __attribute__((aligned(16))) _Float16 RelL[NRELM1 * 72];  // stride 72: de-conflict
    int tid = threadIdx.x;
    if (tid < 72) *(float4*)(RelL + (tid >> 3) * 72 + (tid & 7) * 8)
                      = *(const float4*)(Relh + tid * 8);
    __syncthreads();

    int pair = blockIdx.x * 4 + (tid >> 6);     // wave id
    int lane = tid & 63;
    int wid  = pair * 2 + (lane >> 5);          // node id (2 per wave)
    int s = (lane >> 3) & 3, l = lane & 7;      // slot (4/node), lane-in-slot
    int c8 = l * 8;                             // this lane's 8 channels

    if (wid < NEN) {
        int row = wid;
        int cnt = cntE[row];
        int beg = row * CAPE, end = beg + cnt;
        P4 q; q.f = *(const float4*)(QE + (size_t)row * 128 + 64 + c8);
        float acc[8] = {0.f,0.f,0.f,0.f,0.f,0.f,0.f,0.f};
        float den = 0.f;

        int a0 = beg + s;
        int iA = (a0 < end) ? csrE[a0] : 0;
        int iB = (a0 + 4 < end) ? csrE[a0 + 4] : 0;
        P4 teA, ktA, rlA;
        {
            const _Float16* bA = QE + (size_t)(iA & 0x1FFFF) * 128 + c8;
            teA.f = *(const float4*)bA;
            ktA.f = *(const float4*)(bA + 64);
            rlA.f = *(const float4*)(RelL + (iA >> 17) * 72 + c8);
        }
        int nit = (cnt + 3) >> 2;
        for (int it = 0; it < nit; ++it) {
            P4 teB, ktB, rlB;
            {
                const _Float16* bB = QE + (size_t)(iB & 0x1FFFF) * 128 + c8;
                teB.f = *(const float4*)bB;
                ktB.f = *(const float4*)(bB + 64);
                rlB.f = *(const float4*)(RelL + (iB >> 17) * 72 + c8);
            }
            int a2 = a0 + (it + 2) * 4;
            int iN = (a2 < end) ? csrE[a2] : 0;
            bool act = (a0 + it * 4) < end;
            float sc = 0.f;
#pragma unroll
            for (int i = 0; i < 4; ++i) {
                hv2 km = ktA.h[i] * rlA.h[i];               // v_pk_mul_f16
                sc = __builtin_amdgcn_fdot2(q.h[i], km, sc, false);
            }
            sc += __shfl_xor(sc, 1);                        // head-reduce (4 lanes)
            sc += __shfl_xor(sc, 2);
            float ex = exp2f(sc * 0.25503489f);             // 1/sqrt(32)*log2(e)
            if (!act) ex = 0.f;
            den += ex;
#pragma unroll
            for (int i = 0; i < 4; ++i) {
                hv2 vm = teA.h[i] * rlA.h[i];
                acc[2*i]   += ex * (float)vm.x;             // v_fma_mix_f32
                acc[2*i+1] += ex * (float)vm.y;
            }
            teA = teB; ktA = ktB; rlA = rlB; iB = iN;
        }
        // packed-f16 cross-slot reduce (4 slots within the 32-lane half)
        hv2 pk[4];
#pragma unroll
        for (int i = 0; i < 4; ++i)
            pk[i] = pkrtz(acc[2*i], acc[2*i+1]);
#pragma unroll
        for (int m = 8; m <= 16; m <<= 1) {
#pragma unroll
            for (int i = 0; i < 4; ++i) {
                int v = __shfl_xor(__builtin_bit_cast(int, pk[i]), m);
                pk[i] += __builtin_bit_cast(hv2, v);
            }
            den += __shfl_xor(den, m);
        }
        float af[8];
#pragma unroll
        for (int i = 0; i < 4; ++i) { af[2*i] = (float)pk[i].x; af[2*i+1] = (float)pk[i].y; }
        float invd = (den > 0.f) ? 1.f / den : 0.f;   // deferred softmax division
        float ss = 0.f;
#pragma unroll
        for (int k = 0; k < 8; ++k) { af[k] *= invd; ss += af[k] * af[k]; }
        ss += __shfl_xor(ss, 1); ss += __shfl_xor(ss, 2); ss += __shfl_xor(ss, 4);
        float inv = 1.f / fmaxf(sqrtf(ss), 1e-12f);
#pragma unroll
        for (int k = 0; k < 8; ++k) af[k] *= inv;
        if (s == 0) {                           // one slot per half writes
            if (!LAST) {
                P4 o;
#pragma unroll
                for (int i = 0; i < 4; ++i)
                    o.h[i] = pkrtz(af[2*i], af[2*i+1]);
                *(float4*)(QEn + (size_t)row * 128 + c8) = o.f; // E-part of next hop
            }
            float4 r0 = *(const float4*)(Eres + (size_t)row * 64 + c8);
            float4 r1 = *(const float4*)(Eres + (size_t)row * 64 + c8 + 4);
            r0.x += af[0]; r0.y += af[1]; r0.z += af[2]; r0.w += af[3];
            r1.x += af[4]; r1.y += af[5]; r1.z += af[6]; r1.w += af[7];
            *(float4*)(Eres + (size_t)row * 64 + c8)     = r0;
            *(float4*)(Eres + (size_t)row * 64 + c8 + 4) = r1;
        }
    } else {
        int row = wid - NEN;                    // user node
        int cnt = cntU[row];
        int beg = row * CAPU, end = beg + cnt;
        float acc[8] = {0.f,0.f,0.f,0.f,0.f,0.f,0.f,0.f};
        int a0 = beg + s;
        unsigned long long recA = (a0 < end) ? csrU2[a0] : 0ull;   // rec=0 -> w=+0.0
        unsigned long long recB = (a0 + 4 < end) ? csrU2[a0 + 4] : 0ull;
        P4 teA; teA.f = *(const float4*)(QE + (size_t)(unsigned)recA * 128 + c8);
        int nit = (cnt + 3) >> 2;
        for (int it = 0; it < nit; ++it) {
            P4 teB; teB.f = *(const float4*)(QE + (size_t)(unsigned)recB * 128 + c8);
            int a2 = a0 + (it + 2) * 4;
            unsigned long long recN = (a2 < end) ? csrU2[a2] : 0ull;
            float wA = __uint_as_float((unsigned)(recA >> 32));
#pragma unroll
            for (int i = 0; i < 4; ++i) {
                acc[2*i]   += wA * (float)teA.h[i].x;
                acc[2*i+1] += wA * (float)teA.h[i].y;
            }
            teA = teB; recA = recB; recB = recN;
        }
        hv2 pk[4];
#pragma unroll
        for (int i = 0; i < 4; ++i)
            pk[i] = pkrtz(acc[2*i], acc[2*i+1]);
#pragma unroll
        for (int m = 8; m <= 16; m <<= 1) {
#pragma unroll
            for (int i = 0; i < 4; ++i) {
                int v = __shfl_xor(__builtin_bit_cast(int, pk[i]), m);
                pk[i] += __builtin_bit_cast(hv2, v);
            }
        }
        float af[8];
#pragma unroll
        for (int i = 0; i < 4; ++i) { af[2*i] = (float)pk[i].x; af[2*i+1] = (float)pk[i].y; }
        float ss = 0.f;
#pragma unroll
        for (int k = 0; k < 8; ++k) ss += af[k] * af[k];
        ss += __shfl_xor(ss, 1); ss += __shfl_xor(ss, 2); ss += __shfl_xor(ss, 4);
        float inv = 1.f / fmaxf(sqrtf(ss), 1e-12f);
        if (s == 0) {
            float4 r0 = *(const float4*)(Ures + (size_t)row * 64 + c8);
            float4 r1 = *(const float4*)(Ures + (size_t)row * 64 + c8 + 4);
            r0.x += af[0] * inv; r0.y += af[1] * inv; r0.z += af[2] * inv; r0.w += af[3] * inv;
            r1.x += af[4] * inv; r1.y += af[5] * inv; r1.z += af[6] * inv; r1.w += af[7] * inv;
            *(float4*)(Ures + (size_t)row * 64 + c8)     = r0;
            *(float4*)(Ures + (size_t)row * 64 + c8 + 4) = r1;
        }
    }
}

extern "C" void kernel_launch(void* const* d_in, const int* in_sizes, int n_in,
                              void* d_out, int out_size, void* d_ws, size_t ws_size,
                              hipStream_t stream)
{
    const float* ue = (const float*)d_in[0];
    const float* ee = (const float*)d_in[1];
    const float* re = (const float*)d_in[2];
    const float* wq = (const float*)d_in[3];
    const float* iw = (const float*)d_in[4];
    const int* eidx  = (const int*)d_in[5];
    const int* etype = (const int*)d_in[6];
    const int* ii    = (const int*)d_in[7];

    float* Eres = (float*)d_out;                 // residuals live in d_out directly
    float* Ures = Eres + (size_t)NEN * CH;

    // ws carve (~105 MB):
    // [Relh 2KB][Wt 8KB][QEA 25.6M][QEB 25.6M][cntE][cntU][csrE 25.6M][csrU2 25.6M][dirE][dirU]
    _Float16* Relh = (_Float16*)d_ws;                     // 576 used, 1024 reserved
    _Float16* Wt   = Relh + 1024;                         // 4096 halves (f16 W^T)
    _Float16* QEA  = Wt + 4096;                           // NEN*128 halves
    _Float16* QEB  = QEA + (size_t)NEN * 128;
    int* cntE      = (int*)(QEB + (size_t)NEN * 128);
    int* cntU      = cntE + NEN;
    int* csrE      = cntU + NU;                           // NEN*CAPE ints
    unsigned long long* csrU2 = (unsigned long long*)(csrE + (size_t)NEN * CAPE);
    unsigned* dirE = (unsigned*)(csrU2 + (size_t)NU * CAPU);   // 489*416 u32
    unsigned* dirU = dirE + NBE_BLK * DSTRE;                   // 489*224 u32
    // chunk buffers alias QEB (first written by hop-0 k_fused, strictly after
    // k_pg placement reads complete). 16.0 MB < 25.6 MB.
    int* blkBufE   = (int*)QEB;                                    // 8.0 MB
    unsigned long long* blkBufU =
        (unsigned long long*)((char*)QEB + (size_t)NBE_BLK * CHUNKE * 4);  // 8.0 MB

    k_bin<<<NBE_BLK + NBU_BLK + NSTR_E + NSTR_U + 1, 256, 0, stream>>>(
        ue, ee, re, wq, iw, eidx, etype, ii,
        QEA, Eres, Ures, Relh, Wt, dirE, dirU, blkBufE, blkBufU);
    // placement || hop-0 gemm (independent): co-scheduled in one 512-thread dispatch
    k_pg<<<NPLACE + NGEMM0, 512, 0, stream>>>(dirE, blkBufE, dirU, blkBufU,
                                              cntE, csrE, cntU, csrU2, QEA, Wt);
    k_fused<false><<<(NEN + NU) / 8, 256, 0, stream>>>(cntE, csrE, QEA, Relh,
                                                       QEB, Eres, cntU, csrU2, Ures);
    k_gemm<<<NGEMM, 256, 0, stream>>>(QEB, Wt);
    k_fused<true><<<(NEN + NU) / 8, 256, 0, stream>>>(cntE, csrE, QEB, Relh,
                                                      QEA, Eres, cntU, csrU2, Ures);
}